// Round 1
// baseline (391.712 us; speedup 1.0000x reference)
//
#include <hip/hip_runtime.h>
#include <float.h>

#define DIM 32
#define KCODES 1024
#define NROWS 262144
#define NBLK 256          // kernel A blocks (1024 rows each)

// output offsets (floats, concatenated in reference return order)
#define O_ZQ   0
#define O_CB   8388608
#define O_CL   8388609
#define O_IDX  8388610
#define O_UN   8650754
#define O_EMB  8650755
#define O_CS   8683523
#define O_EA   8684547

// workspace layout (floats)
#define W_PCNT 0                         // [256][1024]
#define W_PSUM (NBLK * KCODES)           // [256][1024*32]
#define W_PCOM (W_PSUM + NBLK * KCODES * DIM) // [256]
#define W_NORM (W_PCOM + NBLK)           // [1024]

// phase-2 LDS layout: stride-33 rows (bank-conflict-free scatter)
#define S_EE   32768                     // phase1: ee[k] at smem[32768+k]
#define S_CNT  33792                     // phase2: counts at smem[33792+k]

__global__ __launch_bounds__(1024, 4) void vq_main(
    const float* __restrict__ z, const float* __restrict__ emb,
    float* __restrict__ out, float* __restrict__ ws)
{
    __shared__ float smem[34816];   // 136 KB, re-used across phases
    __shared__ float red[16];
    const int tid = threadIdx.x;
    const int b   = blockIdx.x;

    // ---- stage embedding to LDS, linear copy (coalesced, conflict-free) ----
    {
        const float4* g4 = reinterpret_cast<const float4*>(emb);
        float4* s4 = reinterpret_cast<float4*>(smem);
        #pragma unroll
        for (int c = 0; c < 8; ++c) s4[tid + c * 1024] = g4[tid + c * 1024];
    }
    // ---- ee[k] for k = tid, numpy pairwise-8 order, from global (L2-hot) ----
    {
        const float* er = emb + tid * DIM;
        float w[32];
        #pragma unroll
        for (int i = 0; i < 32; ++i) { float v = er[i]; w[i] = __fmul_rn(v, v); }
        float r[8];
        #pragma unroll
        for (int j = 0; j < 8; ++j) r[j] = ((w[j] + w[8 + j]) + w[16 + j]) + w[24 + j];
        smem[S_EE + tid] = ((r[0] + r[1]) + (r[2] + r[3])) + ((r[4] + r[5]) + (r[6] + r[7]));
    }
    __syncthreads();

    // ---- load own z row, zz (numpy pairwise-8) ----
    const int row = b * 1024 + tid;
    float zr[32];
    {
        const float4* zg = reinterpret_cast<const float4*>(z + (size_t)row * DIM);
        #pragma unroll
        for (int q = 0; q < 8; ++q) {
            float4 v = zg[q];
            zr[4*q] = v.x; zr[4*q+1] = v.y; zr[4*q+2] = v.z; zr[4*q+3] = v.w;
        }
    }
    float zz;
    {
        float w[32];
        #pragma unroll
        for (int i = 0; i < 32; ++i) w[i] = __fmul_rn(zr[i], zr[i]);
        float r[8];
        #pragma unroll
        for (int j = 0; j < 8; ++j) r[j] = ((w[j] + w[8 + j]) + w[16 + j]) + w[24 + j];
        zz = ((r[0] + r[1]) + (r[2] + r[3])) + ((r[4] + r[5]) + (r[6] + r[7]));
    }

    // ---- distance argmin: d = (zz + ee[k]) - 2*dot  (replicates np rounding) ----
    float bestd = FLT_MAX;
    int   bestk = 0;
    #pragma unroll 4
    for (int k = 0; k < KCODES; ++k) {
        const float4* e4 = reinterpret_cast<const float4*>(&smem[k * DIM]);
        float acc = 0.f;
        #pragma unroll
        for (int q = 0; q < 8; ++q) {
            float4 v = e4[q];
            acc = fmaf(zr[4*q+0], v.x, acc);
            acc = fmaf(zr[4*q+1], v.y, acc);
            acc = fmaf(zr[4*q+2], v.z, acc);
            acc = fmaf(zr[4*q+3], v.w, acc);
        }
        float t1 = zz + smem[S_EE + k];
        float dk = fmaf(-2.0f, acc, t1);     // == fl(t1 - 2*acc), 2*acc exact
        if (dk < bestd) { bestd = dk; bestk = k; }  // strict <: first-min ties like np
    }

    // ---- per-row outputs: index, z_q straight-through, commitment partial ----
    out[O_IDX + row] = (float)bestk;
    float csum = 0.f;
    {
        const float4* eg = reinterpret_cast<const float4*>(emb + bestk * DIM);
        float4* og = reinterpret_cast<float4*>(out + O_ZQ + (size_t)row * DIM);
        #pragma unroll
        for (int q = 0; q < 8; ++q) {
            float4 v = eg[q];
            float x0 = zr[4*q+0], x1 = zr[4*q+1], x2 = zr[4*q+2], x3 = zr[4*q+3];
            float d0 = x0 - v.x, d1 = x1 - v.y, d2 = x2 - v.z, d3 = x3 - v.w;
            csum = fmaf(d0, d0, csum); csum = fmaf(d1, d1, csum);
            csum = fmaf(d2, d2, csum); csum = fmaf(d3, d3, csum);
            float4 o;
            o.x = x0 + (v.x - x0); o.y = x1 + (v.y - x1);
            o.z = x2 + (v.z - x2); o.w = x3 + (v.w - x3);
            og[q] = o;
        }
    }
    // wave reduce commitment partial
    #pragma unroll
    for (int off = 32; off > 0; off >>= 1) csum += __shfl_down(csum, off, 64);
    if ((tid & 63) == 0) red[tid >> 6] = csum;

    __syncthreads();   // all distance-phase LDS reads done -> reuse smem

    // ---- phase 2: block-local histogram + embed-sum (stride-33 rows) ----
    #pragma unroll
    for (int i = 0; i < 33; ++i) smem[tid * 33 + i] = 0.f;
    smem[S_CNT + tid] = 0.f;
    __syncthreads();

    atomicAdd(&smem[S_CNT + bestk], 1.0f);
    #pragma unroll
    for (int i = 0; i < 32; ++i) atomicAdd(&smem[bestk * 33 + i], zr[i]);
    __syncthreads();

    // ---- write per-block partials to workspace ----
    ws[W_PCNT + b * KCODES + tid] = smem[S_CNT + tid];
    {
        float4* p4 = reinterpret_cast<float4*>(ws + W_PSUM + (size_t)b * (KCODES * DIM));
        #pragma unroll
        for (int c = 0; c < 8; ++c) {
            int j = tid + c * 1024;            // float4 index within 32768 floats
            int kk = j >> 3, e0 = (j & 7) * 4; // source row / element
            float4 v;
            v.x = smem[kk * 33 + e0 + 0]; v.y = smem[kk * 33 + e0 + 1];
            v.z = smem[kk * 33 + e0 + 2]; v.w = smem[kk * 33 + e0 + 3];
            p4[j] = v;
        }
    }
    if (tid == 0) {
        float t = 0.f;
        #pragma unroll
        for (int w = 0; w < 16; ++w) t += red[w];
        ws[W_PCOM + b] = t;
    }
}

__global__ __launch_bounds__(1024) void vq_epilogue0(
    const float* __restrict__ cs_in, const float* __restrict__ ws,
    float* __restrict__ out, float* __restrict__ wsw)
{
    __shared__ float s1[1024], s2[1024];
    const int k = threadIdx.x;
    float c = 0.f;
    for (int bb = 0; bb < NBLK; ++bb) c += ws[W_PCNT + bb * KCODES + k];
    float csn = 0.99f * cs_in[k] + 0.01f * c;
    out[O_CS + k] = csn;
    s1[k] = csn;
    s2[k] = (c == 0.f) ? 1.f : 0.f;
    __syncthreads();
    for (int s = 512; s > 0; s >>= 1) {
        if (k < s) { s1[k] += s1[k + s]; s2[k] += s2[k + s]; }
        __syncthreads();
    }
    float n = s1[0];
    float unused = s2[0];
    wsw[W_NORM + k] = n * (csn + 1e-5f) / (n + 1024.f * 1e-5f);
    __syncthreads();
    s1[k] = (k < NBLK) ? ws[W_PCOM + k] : 0.f;
    __syncthreads();
    for (int s = 512; s > 0; s >>= 1) {
        if (k < s) s1[k] += s1[k + s];
        __syncthreads();
    }
    if (k == 0) {
        out[O_CB] = 0.f;
        out[O_CL] = s1[0] / 8388608.f;
        out[O_UN] = unused;
    }
}

__global__ void vq_epilogue1(
    const float* __restrict__ ea, const float* __restrict__ ws,
    float* __restrict__ out)
{
    const int id = blockIdx.x * 128 + threadIdx.x;   // < 32768
    float es = 0.f;
    for (int bb = 0; bb < NBLK; ++bb) es += ws[W_PSUM + (size_t)bb * (KCODES * DIM) + id];
    float ean = 0.99f * ea[id] + 0.01f * es;
    out[O_EA + id] = ean;
    out[O_EMB + id] = ean / ws[W_NORM + (id >> 5)];
}

extern "C" void kernel_launch(void* const* d_in, const int* in_sizes, int n_in,
                              void* d_out, int out_size, void* d_ws, size_t ws_size,
                              hipStream_t stream)
{
    const float* z   = (const float*)d_in[0];
    const float* emb = (const float*)d_in[1];
    const float* ea  = (const float*)d_in[2];
    const float* cs  = (const float*)d_in[3];
    float* out = (float*)d_out;
    float* ws  = (float*)d_ws;

    vq_main<<<NBLK, 1024, 0, stream>>>(z, emb, out, ws);
    vq_epilogue0<<<1, 1024, 0, stream>>>(cs, ws, out, ws);
    vq_epilogue1<<<NBLK, 128, 0, stream>>>(ea, ws, out);
}

// Round 2
// 365.686 us; speedup vs baseline: 1.0712x; 1.0712x over previous
//
#include <hip/hip_runtime.h>
#include <float.h>

#define DIM 32
#define KCODES 1024
#define NROWS 262144
#define NBLK 256

// output offsets (floats, concatenated in reference return order)
#define O_ZQ   0
#define O_CB   8388608
#define O_CL   8388609
#define O_IDX  8388610
#define O_UN   8650754
#define O_EMB  8650755
#define O_CS   8683523
#define O_EA   8684547

// workspace layout (floats)
#define W_PCNT 0                         // [256][1024]
#define W_PSUM (NBLK * KCODES)           // [256][1024*32]
#define W_PCOM (W_PSUM + NBLK * KCODES * DIM) // [256]
#define W_NORM (W_PCOM + NBLK)           // [1024]

#define S_EE 32800                       // ee[] after 1025 padded code rows

// ---------------- kernel A: distance argmin + z_q + commit partial ----------
// 256 blocks x 256 threads, R=4 rows/thread. Codebook (128KB) + ee (4KB) in
// LDS. Each ds_read_b128 of a code row feeds 4 rows' FMAs -> LDS return BW
// (264 cyc/k/CU) hides under VALU issue (~296 cyc/k/SIMD).
__global__ __launch_bounds__(256, 1) void vq_argmin(
    const float* __restrict__ z, const float* __restrict__ emb,
    float* __restrict__ out, float* __restrict__ ws)
{
    __shared__ float smem[33824];   // 1025*32 codes (padded) + 1024 ee
    __shared__ float red[4];
    const int t = threadIdx.x;
    const int b = blockIdx.x;

    // ---- stage codebook to LDS (coalesced) ----
    {
        const float4* g4 = reinterpret_cast<const float4*>(emb);
        float4* s4 = reinterpret_cast<float4*>(smem);
        #pragma unroll
        for (int c = 0; c < 32; ++c) s4[t + c * 256] = g4[t + c * 256];
    }
    // ---- ee[k], numpy pairwise-8, from global (bit-identical to R0) ----
    #pragma unroll
    for (int j = 0; j < 4; ++j) {
        const int code = t + j * 256;
        const float* er = emb + code * DIM;
        float w[32];
        #pragma unroll
        for (int i = 0; i < 32; ++i) { float v = er[i]; w[i] = __fmul_rn(v, v); }
        float r8[8];
        #pragma unroll
        for (int q = 0; q < 8; ++q) r8[q] = ((w[q] + w[8 + q]) + w[16 + q]) + w[24 + q];
        smem[S_EE + code] = ((r8[0] + r8[1]) + (r8[2] + r8[3])) + ((r8[4] + r8[5]) + (r8[6] + r8[7]));
    }
    __syncthreads();

    // ---- load 4 z rows + zz (numpy pairwise-8, per-row identical to R0) ----
    const int base = b * 1024;
    float zr[128];
    #pragma unroll
    for (int r = 0; r < 4; ++r) {
        const float4* zg = reinterpret_cast<const float4*>(z + (size_t)(base + r * 256 + t) * DIM);
        #pragma unroll
        for (int q = 0; q < 8; ++q) {
            float4 v = zg[q];
            zr[r * 32 + 4 * q]     = v.x; zr[r * 32 + 4 * q + 1] = v.y;
            zr[r * 32 + 4 * q + 2] = v.z; zr[r * 32 + 4 * q + 3] = v.w;
        }
    }
    float zz[4];
    #pragma unroll
    for (int r = 0; r < 4; ++r) {
        float w[32];
        #pragma unroll
        for (int i = 0; i < 32; ++i) w[i] = __fmul_rn(zr[r * 32 + i], zr[r * 32 + i]);
        float r8[8];
        #pragma unroll
        for (int q = 0; q < 8; ++q) r8[q] = ((w[q] + w[8 + q]) + w[16 + q]) + w[24 + q];
        zz[r] = ((r8[0] + r8[1]) + (r8[2] + r8[3])) + ((r8[4] + r8[5]) + (r8[6] + r8[7]));
    }

    float bestd[4] = {FLT_MAX, FLT_MAX, FLT_MAX, FLT_MAX};
    int   bestk[4] = {0, 0, 0, 0};
    float4 ea[8], eb[8];

#define LOADE(dst, kk) { const float4* p_ = reinterpret_cast<const float4*>(&smem[(kk) * DIM]); \
    _Pragma("unroll") for (int q = 0; q < 8; ++q) dst[q] = p_[q]; }

#define COMP(e, kk) { float eek_ = smem[S_EE + (kk)]; \
    _Pragma("unroll") for (int r = 0; r < 4; ++r) { \
        float acc = 0.f; \
        _Pragma("unroll") for (int q = 0; q < 8; ++q) { \
            acc = fmaf(zr[r * 32 + 4 * q + 0], e[q].x, acc); \
            acc = fmaf(zr[r * 32 + 4 * q + 1], e[q].y, acc); \
            acc = fmaf(zr[r * 32 + 4 * q + 2], e[q].z, acc); \
            acc = fmaf(zr[r * 32 + 4 * q + 3], e[q].w, acc); } \
        float t1_ = zz[r] + eek_; \
        float dk_ = fmaf(-2.0f, acc, t1_); \
        if (dk_ < bestd[r]) { bestd[r] = dk_; bestk[r] = (kk); } } }

    LOADE(ea, 0)
    for (int k = 0; k < KCODES; k += 2) {
        LOADE(eb, k + 1)
        COMP(ea, k)
        LOADE(ea, k + 2)      // k+2==1024 hits the LDS pad row (never used)
        COMP(eb, k + 1)
    }

    // ---- per-row outputs ----
    float csum = 0.f;
    #pragma unroll
    for (int r = 0; r < 4; ++r) {
        const int row = base + r * 256 + t;
        out[O_IDX + row] = (float)bestk[r];
        const float4* eg = reinterpret_cast<const float4*>(emb + bestk[r] * DIM);
        float4* og = reinterpret_cast<float4*>(out + O_ZQ + (size_t)row * DIM);
        #pragma unroll
        for (int q = 0; q < 8; ++q) {
            float4 v = eg[q];
            float x0 = zr[r * 32 + 4 * q + 0], x1 = zr[r * 32 + 4 * q + 1];
            float x2 = zr[r * 32 + 4 * q + 2], x3 = zr[r * 32 + 4 * q + 3];
            float d0 = x0 - v.x, d1 = x1 - v.y, d2 = x2 - v.z, d3 = x3 - v.w;
            csum = fmaf(d0, d0, csum); csum = fmaf(d1, d1, csum);
            csum = fmaf(d2, d2, csum); csum = fmaf(d3, d3, csum);
            float4 o;
            o.x = x0 + (v.x - x0); o.y = x1 + (v.y - x1);
            o.z = x2 + (v.z - x2); o.w = x3 + (v.w - x3);
            og[q] = o;
        }
    }
    #pragma unroll
    for (int off = 32; off > 0; off >>= 1) csum += __shfl_down(csum, off, 64);
    if ((t & 63) == 0) red[t >> 6] = csum;
    __syncthreads();
    if (t == 0) ws[W_PCOM + b] = ((red[0] + red[1]) + (red[2] + red[3]));
}

// ---------------- kernel S: scatter (counts + embed_sum partials) -----------
__global__ __launch_bounds__(1024) void vq_scatter(
    const float* __restrict__ z, const float* __restrict__ outv,
    float* __restrict__ ws)
{
    __shared__ float smem[34816];   // [1024][33] sums + counts at 33792
    const int t = threadIdx.x;
    const int b = blockIdx.x;
    #pragma unroll
    for (int i = 0; i < 33; ++i) smem[t * 33 + i] = 0.f;
    smem[33792 + t] = 0.f;
    __syncthreads();

    const int row = b * 1024 + t;
    const int kk = (int)outv[O_IDX + row];
    atomicAdd(&smem[33792 + kk], 1.0f);
    const float4* zg = reinterpret_cast<const float4*>(z + (size_t)row * DIM);
    #pragma unroll
    for (int q = 0; q < 8; ++q) {
        float4 v = zg[q];
        atomicAdd(&smem[kk * 33 + 4 * q + 0], v.x);
        atomicAdd(&smem[kk * 33 + 4 * q + 1], v.y);
        atomicAdd(&smem[kk * 33 + 4 * q + 2], v.z);
        atomicAdd(&smem[kk * 33 + 4 * q + 3], v.w);
    }
    __syncthreads();

    ws[W_PCNT + b * KCODES + t] = smem[33792 + t];
    float4* p4 = reinterpret_cast<float4*>(ws + W_PSUM + (size_t)b * (KCODES * DIM));
    #pragma unroll
    for (int c = 0; c < 8; ++c) {
        int j = t + c * 1024;
        int kr = j >> 3, e0 = (j & 7) * 4;
        float4 v;
        v.x = smem[kr * 33 + e0 + 0]; v.y = smem[kr * 33 + e0 + 1];
        v.z = smem[kr * 33 + e0 + 2]; v.w = smem[kr * 33 + e0 + 3];
        p4[j] = v;
    }
}

__global__ __launch_bounds__(1024) void vq_epilogue0(
    const float* __restrict__ cs_in, const float* __restrict__ ws,
    float* __restrict__ out, float* __restrict__ wsw)
{
    __shared__ float s1[1024], s2[1024];
    const int k = threadIdx.x;
    float c = 0.f;
    for (int bb = 0; bb < NBLK; ++bb) c += ws[W_PCNT + bb * KCODES + k];
    float csn = 0.99f * cs_in[k] + 0.01f * c;
    out[O_CS + k] = csn;
    s1[k] = csn;
    s2[k] = (c == 0.f) ? 1.f : 0.f;
    __syncthreads();
    for (int s = 512; s > 0; s >>= 1) {
        if (k < s) { s1[k] += s1[k + s]; s2[k] += s2[k + s]; }
        __syncthreads();
    }
    float n = s1[0];
    float unused = s2[0];
    wsw[W_NORM + k] = n * (csn + 1e-5f) / (n + 1024.f * 1e-5f);
    __syncthreads();
    s1[k] = (k < NBLK) ? ws[W_PCOM + k] : 0.f;
    __syncthreads();
    for (int s = 512; s > 0; s >>= 1) {
        if (k < s) s1[k] += s1[k + s];
        __syncthreads();
    }
    if (k == 0) {
        out[O_CB] = 0.f;
        out[O_CL] = s1[0] / 8388608.f;
        out[O_UN] = unused;
    }
}

__global__ void vq_epilogue1(
    const float* __restrict__ ea, const float* __restrict__ ws,
    float* __restrict__ out)
{
    const int id = blockIdx.x * 128 + threadIdx.x;   // < 32768
    float es = 0.f;
    for (int bb = 0; bb < NBLK; ++bb) es += ws[W_PSUM + (size_t)bb * (KCODES * DIM) + id];
    float ean = 0.99f * ea[id] + 0.01f * es;
    out[O_EA + id] = ean;
    out[O_EMB + id] = ean / ws[W_NORM + (id >> 5)];
}

extern "C" void kernel_launch(void* const* d_in, const int* in_sizes, int n_in,
                              void* d_out, int out_size, void* d_ws, size_t ws_size,
                              hipStream_t stream)
{
    const float* z   = (const float*)d_in[0];
    const float* emb = (const float*)d_in[1];
    const float* ea  = (const float*)d_in[2];
    const float* cs  = (const float*)d_in[3];
    float* out = (float*)d_out;
    float* ws  = (float*)d_ws;

    vq_argmin<<<NBLK, 256, 0, stream>>>(z, emb, out, ws);
    vq_scatter<<<NBLK, 1024, 0, stream>>>(z, out, ws);
    vq_epilogue0<<<1, 1024, 0, stream>>>(cs, ws, out, ws);
    vq_epilogue1<<<NBLK, 128, 0, stream>>>(ea, ws, out);
}

// Round 3
// 185.045 us; speedup vs baseline: 2.1168x; 1.9762x over previous
//
#include <hip/hip_runtime.h>
#include <hip/hip_bf16.h>
#include <float.h>

#define DIM 32
#define KCODES 1024
#define NROWS 262144
#define NBLK 256

// output offsets (floats, reference return order)
#define O_ZQ   0
#define O_CB   8388608
#define O_CL   8388609
#define O_IDX  8388610
#define O_UN   8650754
#define O_EMB  8650755
#define O_CS   8683523
#define O_EA   8684547

// workspace layout (float offsets)
#define W_PCNT 0
#define W_PSUM 262144
#define W_PCOM 8650752
#define W_NORM 8651008
#define W_ZZH  8652032
#define W_EEH  8914176
#define W_BF   8915200   // ushort region: 2 halves x 49152 ushorts (96KB each)

typedef __attribute__((ext_vector_type(8))) short bf16x8;
typedef __attribute__((ext_vector_type(4))) float f32x4;
typedef __attribute__((ext_vector_type(4))) int i32x4;

#define MFMA16 __builtin_amdgcn_mfma_f32_16x16x32_bf16

static __device__ __forceinline__ unsigned short f2bf(float x) {
    __hip_bfloat16 h = __float2bfloat16(x);           // RNE
    return __builtin_bit_cast(unsigned short, h);
}
static __device__ __forceinline__ float bf2f(unsigned short u) {
    unsigned int v = ((unsigned int)u) << 16;
    return __builtin_bit_cast(float, v);
}
// numpy pairwise-8 sum of 32 squares (bit-identical to reference path)
static __device__ __forceinline__ float pw8_sq(const float* x) {
    float w[32];
    #pragma unroll
    for (int i = 0; i < 32; ++i) w[i] = __fmul_rn(x[i], x[i]);
    float r[8];
    #pragma unroll
    for (int j = 0; j < 8; ++j) r[j] = ((w[j] + w[8 + j]) + w[16 + j]) + w[24 + j];
    return ((r[0] + r[1]) + (r[2] + r[3])) + ((r[4] + r[5]) + (r[6] + r[7]));
}

// ---------------- P1: zz/2 per row ----------------
__global__ __launch_bounds__(256) void vq_prep_z(
    const float* __restrict__ z, float* __restrict__ ws)
{
    int row = blockIdx.x * 256 + threadIdx.x;
    float x[32];
    const float4* zg = (const float4*)(z + (size_t)row * DIM);
    #pragma unroll
    for (int q = 0; q < 8; ++q) {
        float4 v = zg[q];
        x[4*q] = v.x; x[4*q+1] = v.y; x[4*q+2] = v.z; x[4*q+3] = v.w;
    }
    ws[W_ZZH + row] = 0.5f * pw8_sq(x);
}

// ---------------- P2: ee/2 + codebook bf16x3 fragments ----------------
__global__ __launch_bounds__(256) void vq_prep_e(
    const float* __restrict__ emb, float* __restrict__ ws)
{
    int c = blockIdx.x * 256 + threadIdx.x;   // grid 4 -> 1024 codes
    float x[32];
    const float4* eg = (const float4*)(emb + (size_t)c * DIM);
    #pragma unroll
    for (int q = 0; q < 8; ++q) {
        float4 v = eg[q];
        x[4*q] = v.x; x[4*q+1] = v.y; x[4*q+2] = v.z; x[4*q+3] = v.w;
    }
    ws[W_EEH + c] = 0.5f * pw8_sq(x);

    unsigned short hb[3][32];
    #pragma unroll
    for (int i = 0; i < 32; ++i) {
        float v = x[i];
        unsigned short h0 = f2bf(v); float f0 = bf2f(h0); float r1 = v - f0;
        unsigned short h1 = f2bf(r1); float f1 = bf2f(h1); float r2 = r1 - f1;
        unsigned short h2 = f2bf(r2);   // exact: z = h0+h1+h2
        hb[0][i] = h0; hb[1][i] = h1; hb[2][i] = h2;
    }
    // B-frag layout for mfma_f32_16x16x32_bf16: lane l holds B[k=(l>>4)*8+e][col=l&15]
    bf16x8* bf = (bf16x8*)(ws + W_BF);
    int ct = c >> 4, cl = c & 15;
    #pragma unroll
    for (int s = 0; s < 3; ++s) {
        #pragma unroll
        for (int j = 0; j < 4; ++j) {        // k-chunk
            bf16x8 pk;
            #pragma unroll
            for (int e = 0; e < 8; ++e) pk[e] = (short)hb[s][j*8 + e];
            bf[(ct*3 + s)*64 + j*16 + cl] = pk;
        }
    }
}

// ---------------- A: MFMA distance argmin -> indices ----------------
__global__ __launch_bounds__(512) void vq_argmin_mfma(
    const float* __restrict__ z, const float* __restrict__ wsc,
    float* __restrict__ out)
{
    __shared__ unsigned short bsh[49152];   // 96KB: 32 ctiles x 3 splits x 64 lanes x 8 bf16
    __shared__ float eesh[1024];
    const int t = threadIdx.x;
    const int lane = t & 63, w = t >> 6;
    const int g = lane >> 4, lr = lane & 15;

    const unsigned short* bfG = (const unsigned short*)(wsc + W_BF);
    const float* zzh = wsc + W_ZZH;

    for (int i = t; i < 1024; i += 512) eesh[i] = wsc[W_EEH + i];

    const int rtbase = blockIdx.x * 64 + w * 8;

    for (int pair = 0; pair < 4; ++pair) {
        const int rt0 = rtbase + pair * 2;
        const int rt1 = rt0 + 1;
        // --- load + exact-split A fragments (lane l: row=l&15, k=(l>>4)*8..+7) ---
        bf16x8 zh0, zm0, zl0, zh1, zm1, zl1;
        float4 zz0, zz1;
        {
            const float* zp0 = z + ((size_t)(rt0*16 + lr))*DIM + g*8;
            const float* zp1 = z + ((size_t)(rt1*16 + lr))*DIM + g*8;
            float4 a0 = *(const float4*)zp0, b0 = *(const float4*)(zp0+4);
            float4 a1 = *(const float4*)zp1, b1 = *(const float4*)(zp1+4);
            float xs0[8] = {a0.x,a0.y,a0.z,a0.w,b0.x,b0.y,b0.z,b0.w};
            float xs1[8] = {a1.x,a1.y,a1.z,a1.w,b1.x,b1.y,b1.z,b1.w};
            #pragma unroll
            for (int e = 0; e < 8; ++e) {
                float v = xs0[e];
                unsigned short h0 = f2bf(v); float f0 = bf2f(h0); float r1 = v - f0;
                unsigned short h1 = f2bf(r1); float f1 = bf2f(h1); float r2 = r1 - f1;
                zh0[e] = (short)h0; zm0[e] = (short)h1; zl0[e] = (short)f2bf(r2);
            }
            #pragma unroll
            for (int e = 0; e < 8; ++e) {
                float v = xs1[e];
                unsigned short h0 = f2bf(v); float f0 = bf2f(h0); float r1 = v - f0;
                unsigned short h1 = f2bf(r1); float f1 = bf2f(h1); float r2 = r1 - f1;
                zh1[e] = (short)h0; zm1[e] = (short)h1; zl1[e] = (short)f2bf(r2);
            }
            zz0 = *(const float4*)(zzh + rt0*16 + g*4);
            zz1 = *(const float4*)(zzh + rt1*16 + g*4);
        }
        float zza0[4] = {zz0.x, zz0.y, zz0.z, zz0.w};
        float zza1[4] = {zz1.x, zz1.y, zz1.z, zz1.w};

        unsigned int Bb0[4], Bb1[4]; int Kk0[4], Kk1[4];
        #pragma unroll
        for (int r = 0; r < 4; ++r) { Bb0[r] = 0xFFFFFFFFu; Bb1[r] = 0xFFFFFFFFu; Kk0[r] = 0; Kk1[r] = 0; }

        for (int half = 0; half < 2; ++half) {
            __syncthreads();   // prior readers done before restage
            {
                const i32x4* src = (const i32x4*)(bfG + half * 49152);
                i32x4* dst = (i32x4*)bsh;
                #pragma unroll
                for (int i = 0; i < 12; ++i) dst[t + i*512] = src[t + i*512];
            }
            __syncthreads();
            const bf16x8* bv = (const bf16x8*)bsh;
            for (int ct = 0; ct < 32; ++ct) {
                bf16x8 eh = bv[(ct*3 + 0)*64 + lane];
                bf16x8 em = bv[(ct*3 + 1)*64 + lane];
                bf16x8 el = bv[(ct*3 + 2)*64 + lane];
                float ee_l = eesh[(half*32 + ct)*16 + lr];
                int kge = (half*32 + ct)*16 + lr;
                f32x4 a0 = {0.f,0.f,0.f,0.f}, a1 = {0.f,0.f,0.f,0.f};
                a0 = MFMA16(zh0, eh, a0, 0,0,0);  a1 = MFMA16(zh1, eh, a1, 0,0,0);
                a0 = MFMA16(zh0, em, a0, 0,0,0);  a1 = MFMA16(zh1, em, a1, 0,0,0);
                a0 = MFMA16(zm0, eh, a0, 0,0,0);  a1 = MFMA16(zm1, eh, a1, 0,0,0);
                a0 = MFMA16(zh0, el, a0, 0,0,0);  a1 = MFMA16(zh1, el, a1, 0,0,0);
                a0 = MFMA16(zl0, eh, a0, 0,0,0);  a1 = MFMA16(zl1, eh, a1, 0,0,0);
                a0 = MFMA16(zm0, em, a0, 0,0,0);  a1 = MFMA16(zm1, em, a1, 0,0,0);
                #pragma unroll
                for (int r = 0; r < 4; ++r) {
                    float v0 = (zza0[r] + ee_l) - a0[r];     // = d/2, >0
                    float v1 = (zza1[r] + ee_l) - a1[r];
                    unsigned int u0 = __builtin_bit_cast(unsigned int, v0);
                    unsigned int u1 = __builtin_bit_cast(unsigned int, v1);
                    bool t0 = u0 < Bb0[r];  Bb0[r] = t0 ? u0 : Bb0[r];  Kk0[r] = t0 ? kge : Kk0[r];
                    bool t1 = u1 < Bb1[r];  Bb1[r] = t1 ? u1 : Bb1[r];  Kk1[r] = t1 ? kge : Kk1[r];
                }
            }
        }
        // --- cross-lane reduce within 16-lane col-groups, tie -> lowest k ---
        #pragma unroll
        for (int r = 0; r < 4; ++r) {
            unsigned int b0 = Bb0[r]; int k0 = Kk0[r];
            unsigned int b1 = Bb1[r]; int k1 = Kk1[r];
            #pragma unroll
            for (int m = 1; m < 16; m <<= 1) {
                unsigned int ob = __shfl_xor((int)b0, m, 16); int ok = __shfl_xor(k0, m, 16);
                bool tk = (ob < b0) || (ob == b0 && ok < k0);
                b0 = tk ? ob : b0; k0 = tk ? ok : k0;
                unsigned int pb = __shfl_xor((int)b1, m, 16); int pk = __shfl_xor(k1, m, 16);
                bool tq = (pb < b1) || (pb == b1 && pk < k1);
                b1 = tq ? pb : b1; k1 = tq ? pk : k1;
            }
            if (lr == 0) {
                out[O_IDX + rt0*16 + g*4 + r] = (float)k0;
                out[O_IDX + rt1*16 + g*4 + r] = (float)k1;
            }
        }
    }
}

// ---------------- S: gather z_q + commitment + scatter partials ----------------
__global__ __launch_bounds__(1024) void vq_scatter(
    const float* __restrict__ z, const float* __restrict__ emb,
    float* __restrict__ out, float* __restrict__ ws)
{
    __shared__ float smem[34816];   // [1024][33] sums + counts at 33792
    __shared__ float red[16];
    const int t = threadIdx.x;
    const int b = blockIdx.x;
    #pragma unroll
    for (int i = 0; i < 33; ++i) smem[t * 33 + i] = 0.f;
    smem[33792 + t] = 0.f;
    __syncthreads();

    const int row = b * 1024 + t;
    const int kk = (int)out[O_IDX + row];
    const float4* zg = (const float4*)(z + (size_t)row * DIM);
    const float4* eg = (const float4*)(emb + (size_t)kk * DIM);
    float4* og = (float4*)(out + O_ZQ + (size_t)row * DIM);
    float zv[32];
    float csum = 0.f;
    #pragma unroll
    for (int q = 0; q < 8; ++q) {
        float4 v = zg[q];
        float4 e = eg[q];
        zv[4*q] = v.x; zv[4*q+1] = v.y; zv[4*q+2] = v.z; zv[4*q+3] = v.w;
        float d0 = v.x - e.x, d1 = v.y - e.y, d2 = v.z - e.z, d3 = v.w - e.w;
        csum = fmaf(d0, d0, csum); csum = fmaf(d1, d1, csum);
        csum = fmaf(d2, d2, csum); csum = fmaf(d3, d3, csum);
        float4 o;
        o.x = v.x + (e.x - v.x); o.y = v.y + (e.y - v.y);
        o.z = v.z + (e.z - v.z); o.w = v.w + (e.w - v.w);
        og[q] = o;
    }
    atomicAdd(&smem[33792 + kk], 1.0f);
    #pragma unroll
    for (int i = 0; i < 32; ++i) atomicAdd(&smem[kk * 33 + i], zv[i]);

    #pragma unroll
    for (int off = 32; off > 0; off >>= 1) csum += __shfl_down(csum, off, 64);
    if ((t & 63) == 0) red[t >> 6] = csum;
    __syncthreads();

    ws[W_PCNT + b * KCODES + t] = smem[33792 + t];
    float4* p4 = (float4*)(ws + W_PSUM + (size_t)b * (KCODES * DIM));
    #pragma unroll
    for (int c = 0; c < 8; ++c) {
        int j = t + c * 1024;
        int kr = j >> 3, e0 = (j & 7) * 4;
        float4 v;
        v.x = smem[kr * 33 + e0 + 0]; v.y = smem[kr * 33 + e0 + 1];
        v.z = smem[kr * 33 + e0 + 2]; v.w = smem[kr * 33 + e0 + 3];
        p4[j] = v;
    }
    if (t == 0) {
        float s = 0.f;
        #pragma unroll
        for (int i = 0; i < 16; ++i) s += red[i];
        ws[W_PCOM + b] = s;
    }
}

__global__ __launch_bounds__(1024) void vq_epilogue0(
    const float* __restrict__ cs_in, const float* __restrict__ ws,
    float* __restrict__ out, float* __restrict__ wsw)
{
    __shared__ float s1[1024], s2[1024];
    const int k = threadIdx.x;
    float c = 0.f;
    for (int bb = 0; bb < NBLK; ++bb) c += ws[W_PCNT + bb * KCODES + k];
    float csn = 0.99f * cs_in[k] + 0.01f * c;
    out[O_CS + k] = csn;
    s1[k] = csn;
    s2[k] = (c == 0.f) ? 1.f : 0.f;
    __syncthreads();
    for (int s = 512; s > 0; s >>= 1) {
        if (k < s) { s1[k] += s1[k + s]; s2[k] += s2[k + s]; }
        __syncthreads();
    }
    float n = s1[0];
    float unused = s2[0];
    wsw[W_NORM + k] = n * (csn + 1e-5f) / (n + 1024.f * 1e-5f);
    __syncthreads();
    s1[k] = (k < NBLK) ? ws[W_PCOM + k] : 0.f;
    __syncthreads();
    for (int s = 512; s > 0; s >>= 1) {
        if (k < s) s1[k] += s1[k + s];
        __syncthreads();
    }
    if (k == 0) {
        out[O_CB] = 0.f;
        out[O_CL] = s1[0] / 8388608.f;
        out[O_UN] = unused;
    }
}

__global__ void vq_epilogue1(
    const float* __restrict__ ea, const float* __restrict__ ws,
    float* __restrict__ out)
{
    const int id = blockIdx.x * 128 + threadIdx.x;   // < 32768
    float es = 0.f;
    for (int bb = 0; bb < NBLK; ++bb) es += ws[W_PSUM + (size_t)bb * (KCODES * DIM) + id];
    float ean = 0.99f * ea[id] + 0.01f * es;
    out[O_EA + id] = ean;
    out[O_EMB + id] = ean / ws[W_NORM + (id >> 5)];
}

extern "C" void kernel_launch(void* const* d_in, const int* in_sizes, int n_in,
                              void* d_out, int out_size, void* d_ws, size_t ws_size,
                              hipStream_t stream)
{
    const float* z   = (const float*)d_in[0];
    const float* emb = (const float*)d_in[1];
    const float* ea  = (const float*)d_in[2];
    const float* cs  = (const float*)d_in[3];
    float* out = (float*)d_out;
    float* ws  = (float*)d_ws;

    vq_prep_z<<<1024, 256, 0, stream>>>(z, ws);
    vq_prep_e<<<4, 256, 0, stream>>>(emb, ws);
    vq_argmin_mfma<<<NBLK, 512, 0, stream>>>(z, ws, out);
    vq_scatter<<<NBLK, 1024, 0, stream>>>(z, emb, out, ws);
    vq_epilogue0<<<1, 1024, 0, stream>>>(cs, ws, out, ws);
    vq_epilogue1<<<NBLK, 128, 0, stream>>>(ea, ws, out);
}